// Round 1
// baseline (539.310 us; speedup 1.0000x reference)
//
#include <hip/hip_runtime.h>

// ---------------------------------------------------------------------------
// SAGE 3-layer GNN.
//   Per layer: S = X@W_self + b (fp32) ; Pt = X@W_neigh (bf16, CHUNK-PLANES)
//              h[i] = act( S[i] + (sum_{j in N_in(i)} P[j]) / max(deg_i,1) )
//   CSR built once, reused 3 layers. Readout fused into layer-3 agg.
//
// Evidence log:
//   R0/R1/R5 agg all ~135-143us profiled despite totally different inner
//   loops (serial scalar / prefetch-1 / straight-line 8-in-flight).
//   VALUBusy ~2%, HBM ~2%, conflicts 0, occ ~45% -> the wall is the per-CU
//   random-row-gather service rate (~274 cyc/edge/CU ~ 1 B/cyc/CU).
//   R7: P in bf16 (256B->128B rows) was NEUTRAL (~150us) -> cost is
//   per-REQUEST, not per-byte. Pivot to reuse:
//   R8 (this round): LDS-resident gather. P stored as 32 dim-pair planes
//   Pt[c][2][M] bf16; each agg block stages one full 40KB plane
//   (10000 nodes x 2 dims) into LDS, gathers become random ds_read_b32.
//   Grid 32 chunks x 32 node-tiles = 1024 blocks = 4/CU (160KB LDS budget).
//   Predicted: agg 150us -> 15-25us, VALUBusy 2.5%->20-40%, some LDS
//   bank conflicts appear (random 4B gathers).
// ---------------------------------------------------------------------------

#define DH 64
#define NG 16
#define NCH 32   // dim-pair chunks (2 dims each)
#define NB  32   // node tiles per chunk
#define MAXN 10240

__device__ __forceinline__ unsigned short f2bf(float f) {
    unsigned int u = __float_as_uint(f);
    unsigned int r = (u + 0x7FFFu + ((u >> 16) & 1u)) >> 16;   // RNE
    return (unsigned short)r;
}
__device__ __forceinline__ float bflo(unsigned int u) { return __uint_as_float(u << 16); }
__device__ __forceinline__ float bfhi(unsigned int u) { return __uint_as_float(u & 0xFFFF0000u); }

__global__ void deg_count_kernel(const int* __restrict__ dst, int* __restrict__ deg, int E) {
    int i = blockIdx.x * blockDim.x + threadIdx.x;
    if (i < E) atomicAdd(&deg[dst[i]], 1);
}

// single-block exclusive prefix scan over deg -> row_start (and cursor copy)
__global__ void scan_kernel(const int* __restrict__ deg, int* __restrict__ row_start,
                            int* __restrict__ cursor, int M) {
    __shared__ int sdata[1024];
    __shared__ int s_base;
    int tid = threadIdx.x;
    if (tid == 0) s_base = 0;
    __syncthreads();
    for (int base = 0; base < M; base += 1024) {
        int v = (base + tid < M) ? deg[base + tid] : 0;
        sdata[tid] = v;
        __syncthreads();
        for (int off = 1; off < 1024; off <<= 1) {
            int t = (tid >= off) ? sdata[tid - off] : 0;
            __syncthreads();
            sdata[tid] += t;
            __syncthreads();
        }
        int excl = sdata[tid] - v;
        if (base + tid < M) {
            int rs = s_base + excl;
            row_start[base + tid] = rs;
            cursor[base + tid] = rs;
        }
        __syncthreads();
        if (tid == 1023) s_base += sdata[1023];
        __syncthreads();
    }
    if (tid == 0) row_start[M] = s_base;
}

__global__ void scatter_kernel(const int* __restrict__ src, const int* __restrict__ dst,
                               int* __restrict__ cursor, int* __restrict__ edge_src, int E) {
    int i = blockIdx.x * blockDim.x + threadIdx.x;
    if (i < E) {
        int d = dst[i];
        int p = atomicAdd(&cursor[d], 1);
        edge_src[p] = src[i];
    }
}

// S = X@Wself + b (fp32, row-major) ; Pt = X@Wneigh (bf16, chunk planes).
// Pt layout: plane c (dims 2c,2c+1): Pt[c*2M + half*M + node], half = dim&1.
// X: MxK row-major, W: Kx64.
template <int K>
__global__ __launch_bounds__(256) void gemm_dual_kernel(
    const float* __restrict__ X, const float* __restrict__ Ws_g,
    const float* __restrict__ Wn_g, const float* __restrict__ bias,
    float* __restrict__ S, unsigned short* __restrict__ Pt, int M) {
    __shared__ float Xs[64][68];   // stride 68: 16B-aligned float4 rows
    __shared__ float Ws[64][68];
    __shared__ float Wn[64][68];
    int tid = threadIdx.x;
    int row0 = blockIdx.x * 64;
    int cx = tid & 15;    // col group: cols cx + 16*i
    int ry = tid >> 4;    // row group: rows 4*ry + j
    float acc_s[4][4] = {{0.f}};
    float acc_n[4][4] = {{0.f}};

    for (int kc = 0; kc < K; kc += 64) {
#pragma unroll
        for (int it = 0; it < 4; ++it) {
            int q = tid + 256 * it;       // 0..1023
            int row = q >> 4;             // 0..63
            int k4 = (q & 15) * 4;        // 0..60
            float4 xv;
            int gr = row0 + row;
            if (gr < M)
                xv = *reinterpret_cast<const float4*>(&X[(size_t)gr * K + kc + k4]);
            else
                xv = make_float4(0.f, 0.f, 0.f, 0.f);
            *reinterpret_cast<float4*>(&Xs[row][k4]) = xv;
            float4 wv = *reinterpret_cast<const float4*>(&Ws_g[(size_t)(kc + row) * 64 + k4]);
            *reinterpret_cast<float4*>(&Ws[row][k4]) = wv;
            float4 nv = *reinterpret_cast<const float4*>(&Wn_g[(size_t)(kc + row) * 64 + k4]);
            *reinterpret_cast<float4*>(&Wn[row][k4]) = nv;
        }
        __syncthreads();
#pragma unroll 4
        for (int kk = 0; kk < 64; ++kk) {
            float a[4], bs[4], bn[4];
#pragma unroll
            for (int j = 0; j < 4; ++j) a[j] = Xs[ry * 4 + j][kk];
#pragma unroll
            for (int i = 0; i < 4; ++i) {
                bs[i] = Ws[kk][cx + 16 * i];
                bn[i] = Wn[kk][cx + 16 * i];
            }
#pragma unroll
            for (int j = 0; j < 4; ++j)
#pragma unroll
                for (int i = 0; i < 4; ++i) {
                    acc_s[j][i] += a[j] * bs[i];
                    acc_n[j][i] += a[j] * bn[i];
                }
        }
        __syncthreads();
    }

    // S epilogue (row-major fp32 + bias)
#pragma unroll
    for (int j = 0; j < 4; ++j) {
        int r = row0 + ry * 4 + j;
        if (r < M) {
#pragma unroll
            for (int i = 0; i < 4; ++i) {
                int col = cx + 16 * i;
                S[(size_t)r * DH + col] = acc_s[j][i] + bias[col];
            }
        }
    }
    // Pt epilogue: each thread owns 4 consecutive rows of column col ->
    // pack into one 8B ushort4 store per column. (r0 % 4 == 0 by construction;
    // alignment needs M even — M=10000.)
    int r0 = row0 + ry * 4;
#pragma unroll
    for (int i = 0; i < 4; ++i) {
        int col = cx + 16 * i;
        size_t base = (size_t)(col >> 1) * (2 * M) + (size_t)(col & 1) * M;
        if (r0 + 3 < M) {
            ushort4 pk;
            pk.x = f2bf(acc_n[0][i]);
            pk.y = f2bf(acc_n[1][i]);
            pk.z = f2bf(acc_n[2][i]);
            pk.w = f2bf(acc_n[3][i]);
            *reinterpret_cast<ushort4*>(&Pt[base + r0]) = pk;
        } else {
#pragma unroll
            for (int j = 0; j < 4; ++j) {
                int r = r0 + j;
                if (r < M) Pt[base + r] = f2bf(acc_n[j][i]);
            }
        }
    }
}

// Aggregation with LDS-resident message plane.
// Block = (chunk c, node-tile): stages plane c (all M nodes, 2 dims, bf16
// interleaved per node -> 4B/node, 40KB) into LDS; every edge gather is a
// random ds_read_b32 instead of a global row gather.
// Wave layout: 4 nodes x 16 edge-lanes; shuffle-reduce over the 16 lanes.
template <bool RELU, bool READOUT>
__global__ __launch_bounds__(256) void agg_kernel(
    const float* __restrict__ S, const unsigned short* __restrict__ Pt,
    const int* __restrict__ row_start, const int* __restrict__ edge_src,
    float* __restrict__ H, const int* __restrict__ graph_id,
    float* __restrict__ gsum, float* __restrict__ gcnt, int M) {
    __shared__ unsigned int sP[MAXN];
    int tid = threadIdx.x;
    int c    = blockIdx.x / NB;    // dim-pair chunk 0..31
    int tile = blockIdx.x % NB;    // node tile

    // stage plane c: interleave half-planes into sP[node] = dim0 | dim1<<16
    {
        const unsigned short* p0s = Pt + (size_t)c * (2 * M);
        const uint2* p0 = reinterpret_cast<const uint2*>(p0s);
        const uint2* p1 = reinterpret_cast<const uint2*>(p0s + M);
        int nq = M >> 2;           // groups of 4 nodes
        for (int j = tid; j < nq; j += 256) {
            uint2 a = p0[j];       // dim0 of nodes 4j..4j+3
            uint2 b = p1[j];       // dim1 of nodes 4j..4j+3
            uint4 o;
            o.x = (a.x & 0xFFFFu) | (b.x << 16);
            o.y = (a.x >> 16)     | (b.x & 0xFFFF0000u);
            o.z = (a.y & 0xFFFFu) | (b.y << 16);
            o.w = (a.y >> 16)     | (b.y & 0xFFFF0000u);
            *reinterpret_cast<uint4*>(&sP[4 * j]) = o;
        }
        for (int j = (nq << 2) + tid; j < M; j += 256)   // generic-M tail
            sP[j] = (unsigned int)p0s[j] | ((unsigned int)p0s[M + j] << 16);
    }
    __syncthreads();

    int w = tid >> 6;          // wave 0..3
    int g = (tid >> 4) & 3;    // node slot within wave
    int t = tid & 15;          // edge lane

    int npb    = (M + NB - 1) / NB;
    int tstart = tile * npb;
    int tend   = min(tstart + npb, M);

    for (int nb = tstart + w * 4; nb < tend; nb += 16) {
        int n = nb + g;
        int e0 = 0, e1 = 0;
        if (n < tend) { e0 = row_start[n]; e1 = row_start[n + 1]; }
        int cl = max(e1 - 1, 0);
        float ax = 0.f, ay = 0.f;
        int e = e0 + t;
        while (__any(e < e1)) {
            int idx = edge_src[min(e, cl)];
            float m = (e < e1) ? 1.f : 0.f;
            unsigned int v = sP[idx];
            ax = fmaf(m, bflo(v), ax);
            ay = fmaf(m, bfhi(v), ay);
            e += 16;
        }
#pragma unroll
        for (int mm = 1; mm <= 8; mm <<= 1) {
            ax += __shfl_xor(ax, mm, 64);
            ay += __shfl_xor(ay, mm, 64);
        }
        if (t == 0 && n < tend) {
            float inv = 1.0f / fmaxf((float)(e1 - e0), 1.0f);
            const float2 s = *reinterpret_cast<const float2*>(&S[(size_t)n * DH + 2 * c]);
            float2 val;
            val.x = s.x + ax * inv;
            val.y = s.y + ay * inv;
            if (RELU) { val.x = fmaxf(val.x, 0.f); val.y = fmaxf(val.y, 0.f); }
            *reinterpret_cast<float2*>(&H[(size_t)n * DH + 2 * c]) = val;
            if (READOUT) {
                int gid = graph_id[n];
                atomicAdd(&gsum[gid * DH + 2 * c + 0], val.x);
                atomicAdd(&gsum[gid * DH + 2 * c + 1], val.y);
                if (c == 0) atomicAdd(&gcnt[gid], 1.0f);
            }
        }
    }
}

// single block of 1024: out_feat = gsum/cnt ; out = out_feat @ W_cls + b_cls
__global__ __launch_bounds__(1024) void readout_kernel(
    const float* __restrict__ gsum, const float* __restrict__ gcnt,
    const float* __restrict__ Wc, const float* __restrict__ bc,
    float* __restrict__ out, float* __restrict__ out_feat) {
    __shared__ float ofs[NG][DH];
    int tid = threadIdx.x;
    int g = tid >> 6, d = tid & 63;
    float of = gsum[tid] / fmaxf(gcnt[g], 1.0f);
    out_feat[tid] = of;
    ofs[g][d] = of;
    __syncthreads();
    if (tid < NG * 2) {
        int gg = tid >> 1, cc = tid & 1;
        float acc = bc[cc];
#pragma unroll 8
        for (int dd = 0; dd < DH; ++dd) acc += ofs[gg][dd] * Wc[dd * 2 + cc];
        out[gg * 2 + cc] = acc;
    }
}

extern "C" void kernel_launch(void* const* d_in, const int* in_sizes, int n_in,
                              void* d_out, int out_size, void* d_ws, size_t ws_size,
                              hipStream_t stream) {
    const float* feat     = (const float*)d_in[0];
    const int*   src      = (const int*)d_in[1];
    const int*   dst      = (const int*)d_in[2];
    const int*   graph_id = (const int*)d_in[3];
    const float* Ws1 = (const float*)d_in[4];
    const float* Wn1 = (const float*)d_in[5];
    const float* b1  = (const float*)d_in[6];
    const float* Ws2 = (const float*)d_in[7];
    const float* Wn2 = (const float*)d_in[8];
    const float* b2  = (const float*)d_in[9];
    const float* Ws3 = (const float*)d_in[10];
    const float* Wn3 = (const float*)d_in[11];
    const float* b3  = (const float*)d_in[12];
    const float* Wc  = (const float*)d_in[13];
    const float* bc  = (const float*)d_in[14];

    const int M = in_sizes[3];   // 10000 nodes
    const int E = in_sizes[1];   // 320000 edges

    float* out      = (float*)d_out;             // 16 x 2
    float* out_feat = out + NG * 2;              // 16 x 64
    float* Hbuf     = out_feat + NG * DH;        // 10000 x 64 (final h)

    // workspace layout (256B-aligned carves)
    char* w = (char*)d_ws;
    size_t off = 0;
    auto carve = [&](size_t bytes) {
        size_t o = off;
        off = (off + bytes + 255) & ~(size_t)255;
        return o;
    };
    int*   deg      = (int*)  (w + carve((size_t)M * 4));
    float* gsum     = (float*)(w + carve((size_t)NG * DH * 4));
    float* gcnt     = (float*)(w + carve((size_t)NG * 4));
    size_t zero_bytes = off;                       // deg + gsum + gcnt
    int*   row_start = (int*)  (w + carve((size_t)(M + 1) * 4));
    int*   cursor    = (int*)  (w + carve((size_t)M * 4));
    int*   edge_src  = (int*)  (w + carve((size_t)E * 4));
    float* Sbuf      = (float*)(w + carve((size_t)M * DH * 4));
    unsigned short* Ptbuf = (unsigned short*)(w + carve((size_t)M * DH * 2));
    (void)ws_size; (void)n_in; (void)out_size;

    (void)hipMemsetAsync(d_ws, 0, zero_bytes, stream);

    int eb = (E + 255) / 256;
    deg_count_kernel<<<eb, 256, 0, stream>>>(dst, deg, E);
    scan_kernel<<<1, 1024, 0, stream>>>(deg, row_start, cursor, M);
    scatter_kernel<<<eb, 256, 0, stream>>>(src, dst, cursor, edge_src, E);

    int gb = (M + 63) / 64;      // gemm blocks
    int ab = NCH * NB;           // agg blocks: 32 chunks x 32 node tiles

    // layer 1 (K=256), relu
    gemm_dual_kernel<256><<<gb, 256, 0, stream>>>(feat, Ws1, Wn1, b1, Sbuf, Ptbuf, M);
    agg_kernel<true, false><<<ab, 256, 0, stream>>>(Sbuf, Ptbuf, row_start, edge_src,
                                                    Hbuf, graph_id, gsum, gcnt, M);
    // layer 2 (K=64), relu
    gemm_dual_kernel<64><<<gb, 256, 0, stream>>>(Hbuf, Ws2, Wn2, b2, Sbuf, Ptbuf, M);
    agg_kernel<true, false><<<ab, 256, 0, stream>>>(Sbuf, Ptbuf, row_start, edge_src,
                                                    Hbuf, graph_id, gsum, gcnt, M);
    // layer 3 (K=64), no relu, fused readout accumulation
    gemm_dual_kernel<64><<<gb, 256, 0, stream>>>(Hbuf, Ws3, Wn3, b3, Sbuf, Ptbuf, M);
    agg_kernel<false, true><<<ab, 256, 0, stream>>>(Sbuf, Ptbuf, row_start, edge_src,
                                                    Hbuf, graph_id, gsum, gcnt, M);

    readout_kernel<<<1, 1024, 0, stream>>>(gsum, gcnt, Wc, bc, out, out_feat);
}

// Round 2
// 410.195 us; speedup vs baseline: 1.3148x; 1.3148x over previous
//
#include <hip/hip_runtime.h>

// ---------------------------------------------------------------------------
// SAGE 3-layer GNN.
//   Per layer: S = X@W_self + b (fp32) ; P = X@W_neigh (bf16 row-major)
//              h[i] = act( S[i] + (sum_{j in N_in(i)} P[j]) / max(deg_i,1) )
//
// Evidence log:
//   R0..R5: global random row-gather agg ~150us profiled. VALU 2%, HBM 2%,
//     occ ~50% -> per-CU random-gather service wall ~274 cyc/edge/CU.
//   R7: P fp32->bf16 NEUTRAL -> per-request cost, not per-byte.
//   R8 FAILED (280us/agg): dim-sliced LDS planes cut per-visit cost to
//     ~17cyc but multiplied edge visits x32 (one per 2-dim chunk).
//   R9 (this round): SRC-BUCKET slicing. P bucket of 1250 rows x 128B =
//     160,000B fits one workgroup's LDS (160KiB). CSR keyed by
//     (dst*8 + src_bucket) -> 80000 short rows (~4 edges). Block =
//     (bucket, dst-tile): stage slice coalesced once, wave-per-dst gathers
//     full 64-dim rows from LDS (lane=dim, ds_read_u16, 2-way = free),
//     ONE coalesced 256B atomicAdd into fp32 Hn per (dst,bucket).
//     Edge visits = E x 1 (32x fewer than R8). Finish (relu(S+Hn/deg))
//     fused into next gemm's X loader; Hn zeroing fused into gemm epilogue.
//     Shfl-based scan replaces barrier scan (M2=80000).
//   Predicted: agg 280 -> 15-40us, conflicts 1.75M -> <300K,
//     WRITE 22.8 -> ~6MB, total live 539 -> ~150-200us.
// ---------------------------------------------------------------------------

#define DH 64
#define NG 16
#define NSB 8        // src buckets
#define DTILES 32    // dst tiles -> grid 8*32 = 256 blocks (1/CU, LDS-capped)
#define MAXNPB 1250  // max nodes per bucket (M <= 10000)

__device__ __forceinline__ unsigned short f2bf(float f) {
    unsigned int u = __float_as_uint(f);
    unsigned int r = (u + 0x7FFFu + ((u >> 16) & 1u)) >> 16;   // RNE
    return (unsigned short)r;
}
__device__ __forceinline__ float bfu(unsigned short v) {
    return __uint_as_float(((unsigned int)v) << 16);
}

// ---- CSR build keyed by (dst*8 + src_bucket) ------------------------------

__global__ void key_count_kernel(const int* __restrict__ src, const int* __restrict__ dst,
                                 int* __restrict__ deg2, int E, int npb8) {
    int i = blockIdx.x * blockDim.x + threadIdx.x;
    if (i < E) {
        int k = dst[i] * NSB + src[i] / npb8;
        atomicAdd(&deg2[k], 1);
    }
}

// single-block shfl-scan over deg2 -> row_start (+cursor copy). 1024 thr.
__global__ __launch_bounds__(1024) void scan_kernel(
    const int* __restrict__ deg2, int* __restrict__ row_start,
    int* __restrict__ cursor, int M2) {
    __shared__ int swave[16];
    __shared__ int sbase;
    int tid = threadIdx.x;
    int lane = tid & 63, wid = tid >> 6;
    if (tid == 0) sbase = 0;
    __syncthreads();
    for (int base = 0; base < M2; base += 4096) {
        int i0 = base + tid * 4;
        int4 v = make_int4(0, 0, 0, 0);
        if (i0 + 3 < M2) {
            v = *reinterpret_cast<const int4*>(&deg2[i0]);
        } else {
            if (i0 + 0 < M2) v.x = deg2[i0 + 0];
            if (i0 + 1 < M2) v.y = deg2[i0 + 1];
            if (i0 + 2 < M2) v.z = deg2[i0 + 2];
            if (i0 + 3 < M2) v.w = deg2[i0 + 3];
        }
        int s4 = v.x + v.y + v.z + v.w;
        int inc = s4;                       // inclusive wave scan
#pragma unroll
        for (int d = 1; d < 64; d <<= 1) {
            int n = __shfl_up(inc, d, 64);
            if (lane >= d) inc += n;
        }
        if (lane == 63) swave[wid] = inc;
        __syncthreads();
        if (wid == 0 && lane < 16) {
            int p = swave[lane];
#pragma unroll
            for (int d = 1; d < 16; d <<= 1) {
                int n = __shfl_up(p, d, 64);
                if (lane >= d) p += n;
            }
            swave[lane] = p;                // inclusive over waves
        }
        __syncthreads();
        int woff = (wid > 0) ? swave[wid - 1] : 0;
        int o0 = sbase + woff + inc - s4;   // exclusive prefix for i0
        int o1 = o0 + v.x;
        int o2 = o1 + v.y;
        int o3 = o2 + v.z;
        if (i0 + 3 < M2) {
            *reinterpret_cast<int4*>(&row_start[i0]) = make_int4(o0, o1, o2, o3);
            *reinterpret_cast<int4*>(&cursor[i0])    = make_int4(o0, o1, o2, o3);
        } else {
            if (i0 + 0 < M2) { row_start[i0 + 0] = o0; cursor[i0 + 0] = o0; }
            if (i0 + 1 < M2) { row_start[i0 + 1] = o1; cursor[i0 + 1] = o1; }
            if (i0 + 2 < M2) { row_start[i0 + 2] = o2; cursor[i0 + 2] = o2; }
            if (i0 + 3 < M2) { row_start[i0 + 3] = o3; cursor[i0 + 3] = o3; }
        }
        __syncthreads();
        if (tid == 1023) sbase += swave[15];
        __syncthreads();
    }
    if (threadIdx.x == 0) row_start[M2] = sbase;
}

__global__ void key_scatter_kernel(const int* __restrict__ src, const int* __restrict__ dst,
                                   int* __restrict__ cursor, int* __restrict__ edge_src,
                                   int E, int npb8) {
    int i = blockIdx.x * blockDim.x + threadIdx.x;
    if (i < E) {
        int s = src[i];
        int k = dst[i] * NSB + s / npb8;
        int p = atomicAdd(&cursor[k], 1);
        edge_src[p] = s;
    }
}

// ---- dual GEMM: S = X@Ws + b (fp32) ; P = X@Wn (bf16 row-major) -----------
// FUSE: X rows are computed on the fly as relu(S_in + Hn_in/deg) (K must be 64).
// Epilogue also zeroes Hn_out rows for the next aggregation.
template <int K, bool FUSE>
__global__ __launch_bounds__(256) void gemm_dual_kernel(
    const float* __restrict__ X, const float* __restrict__ Ws_g,
    const float* __restrict__ Wn_g, const float* __restrict__ bias,
    const float* __restrict__ Hn_in, const int* __restrict__ rs8,
    float* __restrict__ S, unsigned short* __restrict__ P,
    float* __restrict__ Hn_out, int M) {
    __shared__ float Xs[64][68];
    __shared__ float Ws[64][68];
    __shared__ float Wn[64][68];
    int tid = threadIdx.x;
    int row0 = blockIdx.x * 64;
    int cx = tid & 15;
    int ry = tid >> 4;
    float acc_s[4][4] = {{0.f}};
    float acc_n[4][4] = {{0.f}};

    for (int kc = 0; kc < K; kc += 64) {
#pragma unroll
        for (int it = 0; it < 4; ++it) {
            int q = tid + 256 * it;
            int row = q >> 4;
            int k4 = (q & 15) * 4;
            float4 xv = make_float4(0.f, 0.f, 0.f, 0.f);
            int gr = row0 + row;
            if (gr < M) {
                xv = *reinterpret_cast<const float4*>(&X[(size_t)gr * K + kc + k4]);
                if constexpr (FUSE) {   // K==64, kc==0: x = relu(S + Hn/deg)
                    float4 hv = *reinterpret_cast<const float4*>(&Hn_in[(size_t)gr * DH + k4]);
                    int db = rs8[gr * NSB], de = rs8[gr * NSB + NSB];
                    float inv = 1.f / fmaxf((float)(de - db), 1.f);
                    xv.x = fmaxf(fmaf(hv.x, inv, xv.x), 0.f);
                    xv.y = fmaxf(fmaf(hv.y, inv, xv.y), 0.f);
                    xv.z = fmaxf(fmaf(hv.z, inv, xv.z), 0.f);
                    xv.w = fmaxf(fmaf(hv.w, inv, xv.w), 0.f);
                }
            }
            *reinterpret_cast<float4*>(&Xs[row][k4]) = xv;
            float4 wv = *reinterpret_cast<const float4*>(&Ws_g[(size_t)(kc + row) * 64 + k4]);
            *reinterpret_cast<float4*>(&Ws[row][k4]) = wv;
            float4 nv = *reinterpret_cast<const float4*>(&Wn_g[(size_t)(kc + row) * 64 + k4]);
            *reinterpret_cast<float4*>(&Wn[row][k4]) = nv;
        }
        __syncthreads();
#pragma unroll 4
        for (int kk = 0; kk < 64; ++kk) {
            float a[4], bs[4], bn[4];
#pragma unroll
            for (int j = 0; j < 4; ++j) a[j] = Xs[ry * 4 + j][kk];
#pragma unroll
            for (int i = 0; i < 4; ++i) {
                bs[i] = Ws[kk][cx + 16 * i];
                bn[i] = Wn[kk][cx + 16 * i];
            }
#pragma unroll
            for (int j = 0; j < 4; ++j)
#pragma unroll
                for (int i = 0; i < 4; ++i) {
                    acc_s[j][i] += a[j] * bs[i];
                    acc_n[j][i] += a[j] * bn[i];
                }
        }
        __syncthreads();
    }

#pragma unroll
    for (int j = 0; j < 4; ++j) {
        int r = row0 + ry * 4 + j;
        if (r < M) {
#pragma unroll
            for (int i = 0; i < 4; ++i) {
                int col = cx + 16 * i;
                S[(size_t)r * DH + col] = acc_s[j][i] + bias[col];
                P[(size_t)r * DH + col] = f2bf(acc_n[j][i]);
                Hn_out[(size_t)r * DH + col] = 0.f;
            }
        }
    }
}

// ---- aggregation: src-bucket LDS slice, wave-per-(dst,bucket) row ----------
// grid = NSB * DTILES blocks x 1024 threads. LDS = 1250*64 bf16 = 160,000 B.
__global__ __launch_bounds__(1024) void agg_kernel(
    const unsigned short* __restrict__ P, const int* __restrict__ rs8,
    const int* __restrict__ es, float* __restrict__ Hn, int M, int npb8) {
    __shared__ __align__(16) unsigned short sP[MAXNPB * DH];
    int tid = threadIdx.x;
    int sb    = blockIdx.x & (NSB - 1);
    int dtile = blockIdx.x >> 3;
    int s0 = sb * npb8;
    int snodes = min(npb8, M - s0);

    // stage this bucket's P slice (coalesced uint4)
    {
        const uint4* gp = reinterpret_cast<const uint4*>(P + (size_t)s0 * DH);
        int cnt = snodes * 8;   // 128 B/node / 16 B
        for (int j = tid; j < cnt; j += 1024)
            *reinterpret_cast<uint4*>(&sP[j * 8]) = gp[j];
    }
    __syncthreads();

    int lane = tid & 63, wid = tid >> 6;
    int dpb  = (M + DTILES - 1) / DTILES;
    int d0t  = dtile * dpb;
    int dend = min(d0t + dpb, M);

    for (int dst = d0t + wid; dst < dend; dst += 16) {
        int key = dst * NSB + sb;
        int e0 = rs8[key], e1 = rs8[key + 1];
        if (e0 == e1) continue;
        float acc = 0.f;
        int cmax = e1 - 1;
        for (int e = e0; e < e1; e += 4) {
            int i0 = es[min(e + 0, cmax)] - s0;
            int i1 = es[min(e + 1, cmax)] - s0;
            int i2 = es[min(e + 2, cmax)] - s0;
            int i3 = es[min(e + 3, cmax)] - s0;
            float m1 = (e + 1 < e1) ? 1.f : 0.f;
            float m2 = (e + 2 < e1) ? 1.f : 0.f;
            float m3 = (e + 3 < e1) ? 1.f : 0.f;
            float f0 = bfu(sP[(size_t)i0 * DH + lane]);
            float f1 = bfu(sP[(size_t)i1 * DH + lane]);
            float f2 = bfu(sP[(size_t)i2 * DH + lane]);
            float f3 = bfu(sP[(size_t)i3 * DH + lane]);
            acc += f0;                       // e+0 always valid in-loop
            acc = fmaf(m1, f1, acc);
            acc = fmaf(m2, f2, acc);
            acc = fmaf(m3, f3, acc);
        }
        atomicAdd(&Hn[(size_t)dst * DH + lane], acc);   // coalesced 256 B
    }
}

// ---- layer-3 finish: H = S + Hn/deg (no relu) + readout accumulation ------
__global__ __launch_bounds__(256) void finish_kernel(
    const float* __restrict__ S, const float* __restrict__ Hn,
    const int* __restrict__ rs8, const int* __restrict__ graph_id,
    float* __restrict__ H, float* __restrict__ gsum, float* __restrict__ gcnt,
    int M) {
    int i = blockIdx.x * 256 + threadIdx.x;
    if (i >= M * DH) return;
    int dst = i >> 6, d = i & 63;
    int db = rs8[dst * NSB], de = rs8[dst * NSB + NSB];
    float inv = 1.f / fmaxf((float)(de - db), 1.f);
    float val = fmaf(Hn[i], inv, S[i]);
    H[i] = val;
    int gid = graph_id[dst];
    atomicAdd(&gsum[gid * DH + d], val);
    if (d == 0) atomicAdd(&gcnt[gid], 1.0f);
}

// single block of 1024: out_feat = gsum/cnt ; out = out_feat @ W_cls + b_cls
__global__ __launch_bounds__(1024) void readout_kernel(
    const float* __restrict__ gsum, const float* __restrict__ gcnt,
    const float* __restrict__ Wc, const float* __restrict__ bc,
    float* __restrict__ out, float* __restrict__ out_feat) {
    __shared__ float ofs[NG][DH];
    int tid = threadIdx.x;
    int g = tid >> 6, d = tid & 63;
    float of = gsum[tid] / fmaxf(gcnt[g], 1.0f);
    out_feat[tid] = of;
    ofs[g][d] = of;
    __syncthreads();
    if (tid < NG * 2) {
        int gg = tid >> 1, cc = tid & 1;
        float acc = bc[cc];
#pragma unroll 8
        for (int dd = 0; dd < DH; ++dd) acc += ofs[gg][dd] * Wc[dd * 2 + cc];
        out[gg * 2 + cc] = acc;
    }
}

extern "C" void kernel_launch(void* const* d_in, const int* in_sizes, int n_in,
                              void* d_out, int out_size, void* d_ws, size_t ws_size,
                              hipStream_t stream) {
    const float* feat     = (const float*)d_in[0];
    const int*   src      = (const int*)d_in[1];
    const int*   dst      = (const int*)d_in[2];
    const int*   graph_id = (const int*)d_in[3];
    const float* Ws1 = (const float*)d_in[4];
    const float* Wn1 = (const float*)d_in[5];
    const float* b1  = (const float*)d_in[6];
    const float* Ws2 = (const float*)d_in[7];
    const float* Wn2 = (const float*)d_in[8];
    const float* b2  = (const float*)d_in[9];
    const float* Ws3 = (const float*)d_in[10];
    const float* Wn3 = (const float*)d_in[11];
    const float* b3  = (const float*)d_in[12];
    const float* Wc  = (const float*)d_in[13];
    const float* bc  = (const float*)d_in[14];

    const int M  = in_sizes[3];     // 10000 nodes
    const int E  = in_sizes[1];     // 320000 edges
    const int M2 = M * NSB;         // 80000 (dst, bucket) rows
    const int npb8 = (M + NSB - 1) / NSB;   // 1250 (<= MAXNPB)

    float* out      = (float*)d_out;             // 16 x 2
    float* out_feat = out + NG * 2;              // 16 x 64
    float* Hbuf     = out_feat + NG * DH;        // 10000 x 64 (final h)

    // workspace layout (256B-aligned carves)
    char* w = (char*)d_ws;
    size_t off = 0;
    auto carve = [&](size_t bytes) {
        size_t o = off;
        off = (off + bytes + 255) & ~(size_t)255;
        return o;
    };
    int*   deg2  = (int*)  (w + carve((size_t)M2 * 4));
    float* gsum  = (float*)(w + carve((size_t)NG * DH * 4));
    float* gcnt  = (float*)(w + carve((size_t)NG * 4));
    size_t zero_bytes = off;                       // deg2 + gsum + gcnt
    int*   rs8      = (int*)  (w + carve((size_t)(M2 + 1) * 4));
    int*   cursor   = (int*)  (w + carve((size_t)M2 * 4));
    int*   edge_src = (int*)  (w + carve((size_t)E * 4));
    float* Sbuf     = (float*)(w + carve((size_t)M * DH * 4));
    unsigned short* Pbuf = (unsigned short*)(w + carve((size_t)M * DH * 2));
    float* Hn       = (float*)(w + carve((size_t)M * DH * 4));
    (void)ws_size; (void)n_in; (void)out_size;

    (void)hipMemsetAsync(d_ws, 0, zero_bytes, stream);

    int eb = (E + 255) / 256;
    key_count_kernel<<<eb, 256, 0, stream>>>(src, dst, deg2, E, npb8);
    scan_kernel<<<1, 1024, 0, stream>>>(deg2, rs8, cursor, M2);
    key_scatter_kernel<<<eb, 256, 0, stream>>>(src, dst, cursor, edge_src, E, npb8);

    int gb = (M + 63) / 64;          // gemm blocks
    int ab = NSB * DTILES;           // 256 agg blocks (1/CU)
    int fb = (M * DH + 255) / 256;   // finish blocks

    // layer 1 (K=256): X = feat; epilogue zeroes Hn
    gemm_dual_kernel<256, false><<<gb, 256, 0, stream>>>(
        feat, Ws1, Wn1, b1, nullptr, nullptr, Sbuf, Pbuf, Hn, M);
    agg_kernel<<<ab, 1024, 0, stream>>>(Pbuf, rs8, edge_src, Hn, M, npb8);

    // layer 2 (K=64): X = relu(S1 + Hn1/deg) fused; in-block-safe in-place S/Hn
    gemm_dual_kernel<64, true><<<gb, 256, 0, stream>>>(
        Sbuf, Ws2, Wn2, b2, Hn, rs8, Sbuf, Pbuf, Hn, M);
    agg_kernel<<<ab, 1024, 0, stream>>>(Pbuf, rs8, edge_src, Hn, M, npb8);

    // layer 3 (K=64): X = relu(S2 + Hn2/deg) fused
    gemm_dual_kernel<64, true><<<gb, 256, 0, stream>>>(
        Sbuf, Ws3, Wn3, b3, Hn, rs8, Sbuf, Pbuf, Hn, M);
    agg_kernel<<<ab, 1024, 0, stream>>>(Pbuf, rs8, edge_src, Hn, M, npb8);

    // finish layer 3 (no relu) + readout accumulation
    finish_kernel<<<fb, 256, 0, stream>>>(Sbuf, Hn, rs8, graph_id,
                                          Hbuf, gsum, gcnt, M);
    readout_kernel<<<1, 1024, 0, stream>>>(gsum, gcnt, Wc, bc, out, out_feat);
}

// Round 3
// 293.704 us; speedup vs baseline: 1.8362x; 1.3966x over previous
//
#include <hip/hip_runtime.h>

// ---------------------------------------------------------------------------
// SAGE 3-layer GNN.
//   Per layer: S = X@W_self + b (fp32) ; P = X@W_neigh (bf16 row-major)
//              h[i] = act( S[i] + (sum_{j in N_in(i)} P[j]) / max(deg_i,1) )
//
// Evidence log:
//   R0..R5: global random row-gather agg ~150us profiled. VALU 2%, HBM 2%,
//     occ ~50% -> per-CU random-gather service wall ~274 cyc/edge/CU.
//   R7: P fp32->bf16 NEUTRAL -> per-request cost, not per-byte.
//   R8 FAILED (280us/agg): dim-sliced LDS planes cut per-visit cost ~17cyc
//     but multiplied edge visits x32.
//   R9 WIN: src-bucket LDS slicing (8 buckets x 1250 rows x 128B in LDS,
//     CSR keyed by dst*8+bucket, wave-per-row, coalesced 256B Hn atomics).
//     agg left top-5 entirely. NEW WALL: finish_kernel 130us = 640K scalar
//     atomicAdd onto 1024 gsum words (625-way contention), VALU 0.4%.
//   R10 (this round): finish_kernel -> wave-per-chunk. graph_id is SORTED:
//     lane=dim, per-wave running sum in register, flush one coalesced 256B
//     atomicAdd per graph-change (~655 flushes total vs 640K scalar atomics).
//   Predicted: finish 130 -> <=8us, total 410 -> ~280us.
// ---------------------------------------------------------------------------

#define DH 64
#define NG 16
#define NSB 8        // src buckets
#define DTILES 32    // dst tiles -> grid 8*32 = 256 blocks (1/CU, LDS-capped)
#define MAXNPB 1250  // max nodes per bucket (M <= 10000)

__device__ __forceinline__ unsigned short f2bf(float f) {
    unsigned int u = __float_as_uint(f);
    unsigned int r = (u + 0x7FFFu + ((u >> 16) & 1u)) >> 16;   // RNE
    return (unsigned short)r;
}
__device__ __forceinline__ float bfu(unsigned short v) {
    return __uint_as_float(((unsigned int)v) << 16);
}

// ---- CSR build keyed by (dst*8 + src_bucket) ------------------------------

__global__ void key_count_kernel(const int* __restrict__ src, const int* __restrict__ dst,
                                 int* __restrict__ deg2, int E, int npb8) {
    int i = blockIdx.x * blockDim.x + threadIdx.x;
    if (i < E) {
        int k = dst[i] * NSB + src[i] / npb8;
        atomicAdd(&deg2[k], 1);
    }
}

// single-block shfl-scan over deg2 -> row_start (+cursor copy). 1024 thr.
__global__ __launch_bounds__(1024) void scan_kernel(
    const int* __restrict__ deg2, int* __restrict__ row_start,
    int* __restrict__ cursor, int M2) {
    __shared__ int swave[16];
    __shared__ int sbase;
    int tid = threadIdx.x;
    int lane = tid & 63, wid = tid >> 6;
    if (tid == 0) sbase = 0;
    __syncthreads();
    for (int base = 0; base < M2; base += 4096) {
        int i0 = base + tid * 4;
        int4 v = make_int4(0, 0, 0, 0);
        if (i0 + 3 < M2) {
            v = *reinterpret_cast<const int4*>(&deg2[i0]);
        } else {
            if (i0 + 0 < M2) v.x = deg2[i0 + 0];
            if (i0 + 1 < M2) v.y = deg2[i0 + 1];
            if (i0 + 2 < M2) v.z = deg2[i0 + 2];
            if (i0 + 3 < M2) v.w = deg2[i0 + 3];
        }
        int s4 = v.x + v.y + v.z + v.w;
        int inc = s4;                       // inclusive wave scan
#pragma unroll
        for (int d = 1; d < 64; d <<= 1) {
            int n = __shfl_up(inc, d, 64);
            if (lane >= d) inc += n;
        }
        if (lane == 63) swave[wid] = inc;
        __syncthreads();
        if (wid == 0 && lane < 16) {
            int p = swave[lane];
#pragma unroll
            for (int d = 1; d < 16; d <<= 1) {
                int n = __shfl_up(p, d, 64);
                if (lane >= d) p += n;
            }
            swave[lane] = p;                // inclusive over waves
        }
        __syncthreads();
        int woff = (wid > 0) ? swave[wid - 1] : 0;
        int o0 = sbase + woff + inc - s4;   // exclusive prefix for i0
        int o1 = o0 + v.x;
        int o2 = o1 + v.y;
        int o3 = o2 + v.z;
        if (i0 + 3 < M2) {
            *reinterpret_cast<int4*>(&row_start[i0]) = make_int4(o0, o1, o2, o3);
            *reinterpret_cast<int4*>(&cursor[i0])    = make_int4(o0, o1, o2, o3);
        } else {
            if (i0 + 0 < M2) { row_start[i0 + 0] = o0; cursor[i0 + 0] = o0; }
            if (i0 + 1 < M2) { row_start[i0 + 1] = o1; cursor[i0 + 1] = o1; }
            if (i0 + 2 < M2) { row_start[i0 + 2] = o2; cursor[i0 + 2] = o2; }
            if (i0 + 3 < M2) { row_start[i0 + 3] = o3; cursor[i0 + 3] = o3; }
        }
        __syncthreads();
        if (tid == 1023) sbase += swave[15];
        __syncthreads();
    }
    if (threadIdx.x == 0) row_start[M2] = sbase;
}

__global__ void key_scatter_kernel(const int* __restrict__ src, const int* __restrict__ dst,
                                   int* __restrict__ cursor, int* __restrict__ edge_src,
                                   int E, int npb8) {
    int i = blockIdx.x * blockDim.x + threadIdx.x;
    if (i < E) {
        int s = src[i];
        int k = dst[i] * NSB + s / npb8;
        int p = atomicAdd(&cursor[k], 1);
        edge_src[p] = s;
    }
}

// ---- dual GEMM: S = X@Ws + b (fp32) ; P = X@Wn (bf16 row-major) -----------
// FUSE: X rows are computed on the fly as relu(S_in + Hn_in/deg) (K must be 64).
// Epilogue also zeroes Hn_out rows for the next aggregation.
template <int K, bool FUSE>
__global__ __launch_bounds__(256) void gemm_dual_kernel(
    const float* __restrict__ X, const float* __restrict__ Ws_g,
    const float* __restrict__ Wn_g, const float* __restrict__ bias,
    const float* __restrict__ Hn_in, const int* __restrict__ rs8,
    float* __restrict__ S, unsigned short* __restrict__ P,
    float* __restrict__ Hn_out, int M) {
    __shared__ float Xs[64][68];
    __shared__ float Ws[64][68];
    __shared__ float Wn[64][68];
    int tid = threadIdx.x;
    int row0 = blockIdx.x * 64;
    int cx = tid & 15;
    int ry = tid >> 4;
    float acc_s[4][4] = {{0.f}};
    float acc_n[4][4] = {{0.f}};

    for (int kc = 0; kc < K; kc += 64) {
#pragma unroll
        for (int it = 0; it < 4; ++it) {
            int q = tid + 256 * it;
            int row = q >> 4;
            int k4 = (q & 15) * 4;
            float4 xv = make_float4(0.f, 0.f, 0.f, 0.f);
            int gr = row0 + row;
            if (gr < M) {
                xv = *reinterpret_cast<const float4*>(&X[(size_t)gr * K + kc + k4]);
                if constexpr (FUSE) {   // K==64, kc==0: x = relu(S + Hn/deg)
                    float4 hv = *reinterpret_cast<const float4*>(&Hn_in[(size_t)gr * DH + k4]);
                    int db = rs8[gr * NSB], de = rs8[gr * NSB + NSB];
                    float inv = 1.f / fmaxf((float)(de - db), 1.f);
                    xv.x = fmaxf(fmaf(hv.x, inv, xv.x), 0.f);
                    xv.y = fmaxf(fmaf(hv.y, inv, xv.y), 0.f);
                    xv.z = fmaxf(fmaf(hv.z, inv, xv.z), 0.f);
                    xv.w = fmaxf(fmaf(hv.w, inv, xv.w), 0.f);
                }
            }
            *reinterpret_cast<float4*>(&Xs[row][k4]) = xv;
            float4 wv = *reinterpret_cast<const float4*>(&Ws_g[(size_t)(kc + row) * 64 + k4]);
            *reinterpret_cast<float4*>(&Ws[row][k4]) = wv;
            float4 nv = *reinterpret_cast<const float4*>(&Wn_g[(size_t)(kc + row) * 64 + k4]);
            *reinterpret_cast<float4*>(&Wn[row][k4]) = nv;
        }
        __syncthreads();
#pragma unroll 4
        for (int kk = 0; kk < 64; ++kk) {
            float a[4], bs[4], bn[4];
#pragma unroll
            for (int j = 0; j < 4; ++j) a[j] = Xs[ry * 4 + j][kk];
#pragma unroll
            for (int i = 0; i < 4; ++i) {
                bs[i] = Ws[kk][cx + 16 * i];
                bn[i] = Wn[kk][cx + 16 * i];
            }
#pragma unroll
            for (int j = 0; j < 4; ++j)
#pragma unroll
                for (int i = 0; i < 4; ++i) {
                    acc_s[j][i] += a[j] * bs[i];
                    acc_n[j][i] += a[j] * bn[i];
                }
        }
        __syncthreads();
    }

#pragma unroll
    for (int j = 0; j < 4; ++j) {
        int r = row0 + ry * 4 + j;
        if (r < M) {
#pragma unroll
            for (int i = 0; i < 4; ++i) {
                int col = cx + 16 * i;
                S[(size_t)r * DH + col] = acc_s[j][i] + bias[col];
                P[(size_t)r * DH + col] = f2bf(acc_n[j][i]);
                Hn_out[(size_t)r * DH + col] = 0.f;
            }
        }
    }
}

// ---- aggregation: src-bucket LDS slice, wave-per-(dst,bucket) row ----------
// grid = NSB * DTILES blocks x 1024 threads. LDS = 1250*64 bf16 = 160,000 B.
__global__ __launch_bounds__(1024) void agg_kernel(
    const unsigned short* __restrict__ P, const int* __restrict__ rs8,
    const int* __restrict__ es, float* __restrict__ Hn, int M, int npb8) {
    __shared__ __align__(16) unsigned short sP[MAXNPB * DH];
    int tid = threadIdx.x;
    int sb    = blockIdx.x & (NSB - 1);
    int dtile = blockIdx.x >> 3;
    int s0 = sb * npb8;
    int snodes = min(npb8, M - s0);

    // stage this bucket's P slice (coalesced uint4)
    {
        const uint4* gp = reinterpret_cast<const uint4*>(P + (size_t)s0 * DH);
        int cnt = snodes * 8;   // 128 B/node / 16 B
        for (int j = tid; j < cnt; j += 1024)
            *reinterpret_cast<uint4*>(&sP[j * 8]) = gp[j];
    }
    __syncthreads();

    int lane = tid & 63, wid = tid >> 6;
    int dpb  = (M + DTILES - 1) / DTILES;
    int d0t  = dtile * dpb;
    int dend = min(d0t + dpb, M);

    for (int dst = d0t + wid; dst < dend; dst += 16) {
        int key = dst * NSB + sb;
        int e0 = rs8[key], e1 = rs8[key + 1];
        if (e0 == e1) continue;
        float acc = 0.f;
        int cmax = e1 - 1;
        for (int e = e0; e < e1; e += 4) {
            int i0 = es[min(e + 0, cmax)] - s0;
            int i1 = es[min(e + 1, cmax)] - s0;
            int i2 = es[min(e + 2, cmax)] - s0;
            int i3 = es[min(e + 3, cmax)] - s0;
            float m1 = (e + 1 < e1) ? 1.f : 0.f;
            float m2 = (e + 2 < e1) ? 1.f : 0.f;
            float m3 = (e + 3 < e1) ? 1.f : 0.f;
            float f0 = bfu(sP[(size_t)i0 * DH + lane]);
            float f1 = bfu(sP[(size_t)i1 * DH + lane]);
            float f2 = bfu(sP[(size_t)i2 * DH + lane]);
            float f3 = bfu(sP[(size_t)i3 * DH + lane]);
            acc += f0;                       // e+0 always valid in-loop
            acc = fmaf(m1, f1, acc);
            acc = fmaf(m2, f2, acc);
            acc = fmaf(m3, f3, acc);
        }
        atomicAdd(&Hn[(size_t)dst * DH + lane], acc);   // coalesced 256 B
    }
}

// ---- layer-3 finish: H = S + Hn/deg (no relu) + readout accumulation ------
// graph_id is SORTED: wave processes a contiguous node chunk (lane = dim),
// keeps the per-graph partial sum in a register, flushes one coalesced 256B
// atomicAdd per graph-change / chunk-end. ~655 flushes vs 640K scalar atomics.
__global__ __launch_bounds__(256) void finish_kernel(
    const float* __restrict__ S, const float* __restrict__ Hn,
    const int* __restrict__ rs8, const int* __restrict__ graph_id,
    float* __restrict__ H, float* __restrict__ gsum, float* __restrict__ gcnt,
    int M) {
    int lane = threadIdx.x & 63;
    int wid  = blockIdx.x * 4 + (threadIdx.x >> 6);   // global wave id
    int nw   = gridDim.x * 4;
    int cpw  = (M + nw - 1) / nw;
    int n0 = wid * cpw, n1 = min(n0 + cpw, M);
    if (n0 >= n1) return;

    float acc = 0.f;
    int cnt = 0;
    int cur = graph_id[n0];
    for (int n = n0; n < n1; ++n) {
        int gid = graph_id[n];
        if (gid != cur) {
            atomicAdd(&gsum[cur * DH + lane], acc);
            if (lane == 0) atomicAdd(&gcnt[cur], (float)cnt);
            acc = 0.f; cnt = 0; cur = gid;
        }
        int db = rs8[n * NSB], de = rs8[n * NSB + NSB];
        float inv = 1.f / fmaxf((float)(de - db), 1.f);
        size_t o = (size_t)n * DH + lane;
        float val = fmaf(Hn[o], inv, S[o]);
        H[o] = val;
        acc += val;
        ++cnt;
    }
    atomicAdd(&gsum[cur * DH + lane], acc);
    if (lane == 0) atomicAdd(&gcnt[cur], (float)cnt);
}

// single block of 1024: out_feat = gsum/cnt ; out = out_feat @ W_cls + b_cls
__global__ __launch_bounds__(1024) void readout_kernel(
    const float* __restrict__ gsum, const float* __restrict__ gcnt,
    const float* __restrict__ Wc, const float* __restrict__ bc,
    float* __restrict__ out, float* __restrict__ out_feat) {
    __shared__ float ofs[NG][DH];
    int tid = threadIdx.x;
    int g = tid >> 6, d = tid & 63;
    float of = gsum[tid] / fmaxf(gcnt[g], 1.0f);
    out_feat[tid] = of;
    ofs[g][d] = of;
    __syncthreads();
    if (tid < NG * 2) {
        int gg = tid >> 1, cc = tid & 1;
        float acc = bc[cc];
#pragma unroll 8
        for (int dd = 0; dd < DH; ++dd) acc += ofs[gg][dd] * Wc[dd * 2 + cc];
        out[gg * 2 + cc] = acc;
    }
}

extern "C" void kernel_launch(void* const* d_in, const int* in_sizes, int n_in,
                              void* d_out, int out_size, void* d_ws, size_t ws_size,
                              hipStream_t stream) {
    const float* feat     = (const float*)d_in[0];
    const int*   src      = (const int*)d_in[1];
    const int*   dst      = (const int*)d_in[2];
    const int*   graph_id = (const int*)d_in[3];
    const float* Ws1 = (const float*)d_in[4];
    const float* Wn1 = (const float*)d_in[5];
    const float* b1  = (const float*)d_in[6];
    const float* Ws2 = (const float*)d_in[7];
    const float* Wn2 = (const float*)d_in[8];
    const float* b2  = (const float*)d_in[9];
    const float* Ws3 = (const float*)d_in[10];
    const float* Wn3 = (const float*)d_in[11];
    const float* b3  = (const float*)d_in[12];
    const float* Wc  = (const float*)d_in[13];
    const float* bc  = (const float*)d_in[14];

    const int M  = in_sizes[3];     // 10000 nodes
    const int E  = in_sizes[1];     // 320000 edges
    const int M2 = M * NSB;         // 80000 (dst, bucket) rows
    const int npb8 = (M + NSB - 1) / NSB;   // 1250 (<= MAXNPB)

    float* out      = (float*)d_out;             // 16 x 2
    float* out_feat = out + NG * 2;              // 16 x 64
    float* Hbuf     = out_feat + NG * DH;        // 10000 x 64 (final h)

    // workspace layout (256B-aligned carves)
    char* w = (char*)d_ws;
    size_t off = 0;
    auto carve = [&](size_t bytes) {
        size_t o = off;
        off = (off + bytes + 255) & ~(size_t)255;
        return o;
    };
    int*   deg2  = (int*)  (w + carve((size_t)M2 * 4));
    float* gsum  = (float*)(w + carve((size_t)NG * DH * 4));
    float* gcnt  = (float*)(w + carve((size_t)NG * 4));
    size_t zero_bytes = off;                       // deg2 + gsum + gcnt
    int*   rs8      = (int*)  (w + carve((size_t)(M2 + 1) * 4));
    int*   cursor   = (int*)  (w + carve((size_t)M2 * 4));
    int*   edge_src = (int*)  (w + carve((size_t)E * 4));
    float* Sbuf     = (float*)(w + carve((size_t)M * DH * 4));
    unsigned short* Pbuf = (unsigned short*)(w + carve((size_t)M * DH * 2));
    float* Hn       = (float*)(w + carve((size_t)M * DH * 4));
    (void)ws_size; (void)n_in; (void)out_size;

    (void)hipMemsetAsync(d_ws, 0, zero_bytes, stream);

    int eb = (E + 255) / 256;
    key_count_kernel<<<eb, 256, 0, stream>>>(src, dst, deg2, E, npb8);
    scan_kernel<<<1, 1024, 0, stream>>>(deg2, rs8, cursor, M2);
    key_scatter_kernel<<<eb, 256, 0, stream>>>(src, dst, cursor, edge_src, E, npb8);

    int gb = (M + 63) / 64;          // gemm blocks
    int ab = NSB * DTILES;           // 256 agg blocks (1/CU)
    int fb = 160;                    // finish: 640 waves, ~16 nodes/wave

    // layer 1 (K=256): X = feat; epilogue zeroes Hn
    gemm_dual_kernel<256, false><<<gb, 256, 0, stream>>>(
        feat, Ws1, Wn1, b1, nullptr, nullptr, Sbuf, Pbuf, Hn, M);
    agg_kernel<<<ab, 1024, 0, stream>>>(Pbuf, rs8, edge_src, Hn, M, npb8);

    // layer 2 (K=64): X = relu(S1 + Hn1/deg) fused; in-place S/Hn is
    // block-safe (each block reads only its own rows before writing them)
    gemm_dual_kernel<64, true><<<gb, 256, 0, stream>>>(
        Sbuf, Ws2, Wn2, b2, Hn, rs8, Sbuf, Pbuf, Hn, M);
    agg_kernel<<<ab, 1024, 0, stream>>>(Pbuf, rs8, edge_src, Hn, M, npb8);

    // layer 3 (K=64): X = relu(S2 + Hn2/deg) fused
    gemm_dual_kernel<64, true><<<gb, 256, 0, stream>>>(
        Sbuf, Ws3, Wn3, b3, Hn, rs8, Sbuf, Pbuf, Hn, M);
    agg_kernel<<<ab, 1024, 0, stream>>>(Pbuf, rs8, edge_src, Hn, M, npb8);

    // finish layer 3 (no relu) + readout accumulation
    finish_kernel<<<fb, 256, 0, stream>>>(Sbuf, Hn, rs8, graph_id,
                                          Hbuf, gsum, gcnt, M);
    readout_kernel<<<1, 1024, 0, stream>>>(gsum, gcnt, Wc, bc, out, out_feat);
}

// Round 4
// 255.869 us; speedup vs baseline: 2.1078x; 1.1479x over previous
//
#include <hip/hip_runtime.h>

// ---------------------------------------------------------------------------
// SAGE 3-layer GNN.
//   Per layer: S = X@W_self + b (fp32) ; P = X@W_neigh (bf16 row-major)
//              h[i] = act( S[i] + (sum_{j in N_in(i)} P[j]) / max(deg_i,1) )
//
// Evidence log:
//   R0..R5: global random row-gather agg ~150us profiled. VALU 2%, HBM 2%,
//     occ ~50% -> per-CU random-gather service wall ~274 cyc/edge/CU.
//   R7: P fp32->bf16 NEUTRAL -> per-request cost, not per-byte.
//   R8 FAILED (280us/agg): dim-sliced LDS planes multiplied edge visits x32.
//   R9 WIN: src-bucket LDS slicing (8 buckets x 1250 rows x 128B in LDS,
//     CSR keyed by dst*8+bucket, wave-per-row, coalesced 256B Hn atomics).
//   R10 WIN: finish_kernel 130->off-list. graph_id SORTED: per-wave register
//     accumulation, one coalesced atomic flush per graph-change.
//     Top-5 now = harness 268MB workspace re-poison fill (41us, not ours).
//   R11 (this round): CSR build 3 kernels -> 1. Single-block scan_kernel
//     (~33us on ONE CU) deleted: fixed-capacity slot layout, CAP=32 slots
//     per (dst,bucket) row (Poisson(4) tail ~1e-19; agg clamps cnt<=CAP so
//     memory-safe regardless). build = one edge sweep:
//     p=atomicAdd(cnt8[key]); es[key*32+p]=src. deg = sum of 8 cnts.
//   Predicted: 294 -> ~235-255us, build_kernel ~10-15us profiled.
// ---------------------------------------------------------------------------

#define DH 64
#define NG 16
#define NSB 8        // src buckets
#define DTILES 32    // dst tiles -> grid 8*32 = 256 blocks (1/CU, LDS-capped)
#define MAXNPB 1250  // max nodes per bucket (M <= 10000)
#define CAP 32       // edge slots per (dst,bucket) row

__device__ __forceinline__ unsigned short f2bf(float f) {
    unsigned int u = __float_as_uint(f);
    unsigned int r = (u + 0x7FFFu + ((u >> 16) & 1u)) >> 16;   // RNE
    return (unsigned short)r;
}
__device__ __forceinline__ float bfu(unsigned short v) {
    return __uint_as_float(((unsigned int)v) << 16);
}
__device__ __forceinline__ int deg8(const int* __restrict__ cnt8, int n) {
    const int4* cp = reinterpret_cast<const int4*>(&cnt8[n * NSB]);
    int4 c0 = cp[0], c1 = cp[1];
    return c0.x + c0.y + c0.z + c0.w + c1.x + c1.y + c1.z + c1.w;
}

// ---- one-pass CSR build: count + place into fixed-capacity slots ----------
__global__ void build_kernel(const int* __restrict__ src, const int* __restrict__ dst,
                             int* __restrict__ cnt8, int* __restrict__ es,
                             int E, int npb8) {
    int i = blockIdx.x * blockDim.x + threadIdx.x;
    if (i < E) {
        int s = src[i];
        int k = dst[i] * NSB + s / npb8;
        int p = atomicAdd(&cnt8[k], 1);
        if (p < CAP) es[(size_t)k * CAP + p] = s;   // slot write (memory-safe)
    }
}

// ---- dual GEMM: S = X@Ws + b (fp32) ; P = X@Wn (bf16 row-major) -----------
// FUSE: X rows are computed on the fly as relu(S_in + Hn_in/deg) (K must be 64).
// Epilogue also zeroes Hn_out rows for the next aggregation.
template <int K, bool FUSE>
__global__ __launch_bounds__(256) void gemm_dual_kernel(
    const float* __restrict__ X, const float* __restrict__ Ws_g,
    const float* __restrict__ Wn_g, const float* __restrict__ bias,
    const float* __restrict__ Hn_in, const int* __restrict__ cnt8,
    float* __restrict__ S, unsigned short* __restrict__ P,
    float* __restrict__ Hn_out, int M) {
    __shared__ float Xs[64][68];
    __shared__ float Ws[64][68];
    __shared__ float Wn[64][68];
    int tid = threadIdx.x;
    int row0 = blockIdx.x * 64;
    int cx = tid & 15;
    int ry = tid >> 4;
    float acc_s[4][4] = {{0.f}};
    float acc_n[4][4] = {{0.f}};

    for (int kc = 0; kc < K; kc += 64) {
#pragma unroll
        for (int it = 0; it < 4; ++it) {
            int q = tid + 256 * it;
            int row = q >> 4;
            int k4 = (q & 15) * 4;
            float4 xv = make_float4(0.f, 0.f, 0.f, 0.f);
            int gr = row0 + row;
            if (gr < M) {
                xv = *reinterpret_cast<const float4*>(&X[(size_t)gr * K + kc + k4]);
                if constexpr (FUSE) {   // K==64, kc==0: x = relu(S + Hn/deg)
                    float4 hv = *reinterpret_cast<const float4*>(&Hn_in[(size_t)gr * DH + k4]);
                    float inv = 1.f / fmaxf((float)deg8(cnt8, gr), 1.f);
                    xv.x = fmaxf(fmaf(hv.x, inv, xv.x), 0.f);
                    xv.y = fmaxf(fmaf(hv.y, inv, xv.y), 0.f);
                    xv.z = fmaxf(fmaf(hv.z, inv, xv.z), 0.f);
                    xv.w = fmaxf(fmaf(hv.w, inv, xv.w), 0.f);
                }
            }
            *reinterpret_cast<float4*>(&Xs[row][k4]) = xv;
            float4 wv = *reinterpret_cast<const float4*>(&Ws_g[(size_t)(kc + row) * 64 + k4]);
            *reinterpret_cast<float4*>(&Ws[row][k4]) = wv;
            float4 nv = *reinterpret_cast<const float4*>(&Wn_g[(size_t)(kc + row) * 64 + k4]);
            *reinterpret_cast<float4*>(&Wn[row][k4]) = nv;
        }
        __syncthreads();
#pragma unroll 4
        for (int kk = 0; kk < 64; ++kk) {
            float a[4], bs[4], bn[4];
#pragma unroll
            for (int j = 0; j < 4; ++j) a[j] = Xs[ry * 4 + j][kk];
#pragma unroll
            for (int i = 0; i < 4; ++i) {
                bs[i] = Ws[kk][cx + 16 * i];
                bn[i] = Wn[kk][cx + 16 * i];
            }
#pragma unroll
            for (int j = 0; j < 4; ++j)
#pragma unroll
                for (int i = 0; i < 4; ++i) {
                    acc_s[j][i] += a[j] * bs[i];
                    acc_n[j][i] += a[j] * bn[i];
                }
        }
        __syncthreads();
    }

#pragma unroll
    for (int j = 0; j < 4; ++j) {
        int r = row0 + ry * 4 + j;
        if (r < M) {
#pragma unroll
            for (int i = 0; i < 4; ++i) {
                int col = cx + 16 * i;
                S[(size_t)r * DH + col] = acc_s[j][i] + bias[col];
                P[(size_t)r * DH + col] = f2bf(acc_n[j][i]);
                Hn_out[(size_t)r * DH + col] = 0.f;
            }
        }
    }
}

// ---- aggregation: src-bucket LDS slice, wave-per-(dst,bucket) row ----------
// grid = NSB * DTILES blocks x 1024 threads. LDS = 1250*64 bf16 = 160,000 B.
__global__ __launch_bounds__(1024) void agg_kernel(
    const unsigned short* __restrict__ P, const int* __restrict__ cnt8,
    const int* __restrict__ es, float* __restrict__ Hn, int M, int npb8) {
    __shared__ __align__(16) unsigned short sP[MAXNPB * DH];
    int tid = threadIdx.x;
    int sb    = blockIdx.x & (NSB - 1);
    int dtile = blockIdx.x >> 3;
    int s0 = sb * npb8;
    int snodes = min(npb8, M - s0);

    // stage this bucket's P slice (coalesced uint4)
    {
        const uint4* gp = reinterpret_cast<const uint4*>(P + (size_t)s0 * DH);
        int cnt = snodes * 8;   // 128 B/node / 16 B
        for (int j = tid; j < cnt; j += 1024)
            *reinterpret_cast<uint4*>(&sP[j * 8]) = gp[j];
    }
    __syncthreads();

    int lane = tid & 63, wid = tid >> 6;
    int dpb  = (M + DTILES - 1) / DTILES;
    int d0t  = dtile * dpb;
    int dend = min(d0t + dpb, M);

    for (int dst = d0t + wid; dst < dend; dst += 16) {
        int key = dst * NSB + sb;
        int cnt = min(cnt8[key], CAP);
        if (cnt == 0) continue;
        size_t base = (size_t)key * CAP;
        float acc = 0.f;
        int cmax = cnt - 1;
        for (int e = 0; e < cnt; e += 4) {
            int i0 = es[base + min(e + 0, cmax)] - s0;
            int i1 = es[base + min(e + 1, cmax)] - s0;
            int i2 = es[base + min(e + 2, cmax)] - s0;
            int i3 = es[base + min(e + 3, cmax)] - s0;
            float m1 = (e + 1 < cnt) ? 1.f : 0.f;
            float m2 = (e + 2 < cnt) ? 1.f : 0.f;
            float m3 = (e + 3 < cnt) ? 1.f : 0.f;
            float f0 = bfu(sP[(size_t)i0 * DH + lane]);
            float f1 = bfu(sP[(size_t)i1 * DH + lane]);
            float f2 = bfu(sP[(size_t)i2 * DH + lane]);
            float f3 = bfu(sP[(size_t)i3 * DH + lane]);
            acc += f0;                       // e+0 always valid in-loop
            acc = fmaf(m1, f1, acc);
            acc = fmaf(m2, f2, acc);
            acc = fmaf(m3, f3, acc);
        }
        atomicAdd(&Hn[(size_t)dst * DH + lane], acc);   // coalesced 256 B
    }
}

// ---- layer-3 finish: H = S + Hn/deg (no relu) + readout accumulation ------
// graph_id is SORTED: wave processes a contiguous node chunk (lane = dim),
// keeps the per-graph partial sum in a register, flushes one coalesced 256B
// atomicAdd per graph-change / chunk-end. ~655 flushes vs 640K scalar atomics.
__global__ __launch_bounds__(256) void finish_kernel(
    const float* __restrict__ S, const float* __restrict__ Hn,
    const int* __restrict__ cnt8, const int* __restrict__ graph_id,
    float* __restrict__ H, float* __restrict__ gsum, float* __restrict__ gcnt,
    int M) {
    int lane = threadIdx.x & 63;
    int wid  = blockIdx.x * 4 + (threadIdx.x >> 6);   // global wave id
    int nw   = gridDim.x * 4;
    int cpw  = (M + nw - 1) / nw;
    int n0 = wid * cpw, n1 = min(n0 + cpw, M);
    if (n0 >= n1) return;

    float acc = 0.f;
    int cnt = 0;
    int cur = graph_id[n0];
    for (int n = n0; n < n1; ++n) {
        int gid = graph_id[n];
        if (gid != cur) {
            atomicAdd(&gsum[cur * DH + lane], acc);
            if (lane == 0) atomicAdd(&gcnt[cur], (float)cnt);
            acc = 0.f; cnt = 0; cur = gid;
        }
        float inv = 1.f / fmaxf((float)deg8(cnt8, n), 1.f);
        size_t o = (size_t)n * DH + lane;
        float val = fmaf(Hn[o], inv, S[o]);
        H[o] = val;
        acc += val;
        ++cnt;
    }
    atomicAdd(&gsum[cur * DH + lane], acc);
    if (lane == 0) atomicAdd(&gcnt[cur], (float)cnt);
}

// single block of 1024: out_feat = gsum/cnt ; out = out_feat @ W_cls + b_cls
__global__ __launch_bounds__(1024) void readout_kernel(
    const float* __restrict__ gsum, const float* __restrict__ gcnt,
    const float* __restrict__ Wc, const float* __restrict__ bc,
    float* __restrict__ out, float* __restrict__ out_feat) {
    __shared__ float ofs[NG][DH];
    int tid = threadIdx.x;
    int g = tid >> 6, d = tid & 63;
    float of = gsum[tid] / fmaxf(gcnt[g], 1.0f);
    out_feat[tid] = of;
    ofs[g][d] = of;
    __syncthreads();
    if (tid < NG * 2) {
        int gg = tid >> 1, cc = tid & 1;
        float acc = bc[cc];
#pragma unroll 8
        for (int dd = 0; dd < DH; ++dd) acc += ofs[gg][dd] * Wc[dd * 2 + cc];
        out[gg * 2 + cc] = acc;
    }
}

extern "C" void kernel_launch(void* const* d_in, const int* in_sizes, int n_in,
                              void* d_out, int out_size, void* d_ws, size_t ws_size,
                              hipStream_t stream) {
    const float* feat     = (const float*)d_in[0];
    const int*   src      = (const int*)d_in[1];
    const int*   dst      = (const int*)d_in[2];
    const int*   graph_id = (const int*)d_in[3];
    const float* Ws1 = (const float*)d_in[4];
    const float* Wn1 = (const float*)d_in[5];
    const float* b1  = (const float*)d_in[6];
    const float* Ws2 = (const float*)d_in[7];
    const float* Wn2 = (const float*)d_in[8];
    const float* b2  = (const float*)d_in[9];
    const float* Ws3 = (const float*)d_in[10];
    const float* Wn3 = (const float*)d_in[11];
    const float* b3  = (const float*)d_in[12];
    const float* Wc  = (const float*)d_in[13];
    const float* bc  = (const float*)d_in[14];

    const int M  = in_sizes[3];     // 10000 nodes
    const int E  = in_sizes[1];     // 320000 edges
    const int M2 = M * NSB;         // 80000 (dst, bucket) rows
    const int npb8 = (M + NSB - 1) / NSB;   // 1250 (<= MAXNPB)

    float* out      = (float*)d_out;             // 16 x 2
    float* out_feat = out + NG * 2;              // 16 x 64
    float* Hbuf     = out_feat + NG * DH;        // 10000 x 64 (final h)

    // workspace layout (256B-aligned carves)
    char* w = (char*)d_ws;
    size_t off = 0;
    auto carve = [&](size_t bytes) {
        size_t o = off;
        off = (off + bytes + 255) & ~(size_t)255;
        return o;
    };
    int*   cnt8  = (int*)  (w + carve((size_t)M2 * 4));
    float* gsum  = (float*)(w + carve((size_t)NG * DH * 4));
    float* gcnt  = (float*)(w + carve((size_t)NG * 4));
    size_t zero_bytes = off;                       // cnt8 + gsum + gcnt
    int*   es    = (int*)  (w + carve((size_t)M2 * CAP * 4));   // 10.24 MB
    float* Sbuf  = (float*)(w + carve((size_t)M * DH * 4));
    unsigned short* Pbuf = (unsigned short*)(w + carve((size_t)M * DH * 2));
    float* Hn    = (float*)(w + carve((size_t)M * DH * 4));
    (void)ws_size; (void)n_in; (void)out_size;

    (void)hipMemsetAsync(d_ws, 0, zero_bytes, stream);

    int eb = (E + 255) / 256;
    build_kernel<<<eb, 256, 0, stream>>>(src, dst, cnt8, es, E, npb8);

    int gb = (M + 63) / 64;          // gemm blocks
    int ab = NSB * DTILES;           // 256 agg blocks (1/CU)
    int fb = 160;                    // finish: 640 waves, ~16 nodes/wave

    // layer 1 (K=256): X = feat; epilogue zeroes Hn
    gemm_dual_kernel<256, false><<<gb, 256, 0, stream>>>(
        feat, Ws1, Wn1, b1, nullptr, nullptr, Sbuf, Pbuf, Hn, M);
    agg_kernel<<<ab, 1024, 0, stream>>>(Pbuf, cnt8, es, Hn, M, npb8);

    // layer 2 (K=64): X = relu(S1 + Hn1/deg) fused; in-place S/Hn is
    // block-safe (each block reads only its own rows before writing them)
    gemm_dual_kernel<64, true><<<gb, 256, 0, stream>>>(
        Sbuf, Ws2, Wn2, b2, Hn, cnt8, Sbuf, Pbuf, Hn, M);
    agg_kernel<<<ab, 1024, 0, stream>>>(Pbuf, cnt8, es, Hn, M, npb8);

    // layer 3 (K=64): X = relu(S2 + Hn2/deg) fused
    gemm_dual_kernel<64, true><<<gb, 256, 0, stream>>>(
        Sbuf, Ws3, Wn3, b3, Hn, cnt8, Sbuf, Pbuf, Hn, M);
    agg_kernel<<<ab, 1024, 0, stream>>>(Pbuf, cnt8, es, Hn, M, npb8);

    // finish layer 3 (no relu) + readout accumulation
    finish_kernel<<<fb, 256, 0, stream>>>(Sbuf, Hn, cnt8, graph_id,
                                          Hbuf, gsum, gcnt, M);
    readout_kernel<<<1, 1024, 0, stream>>>(gsum, gcnt, Wc, bc, out, out_feat);
}